// Round 6
// baseline (808.764 us; speedup 1.0000x reference)
//
#include <hip/hip_runtime.h>
#include <math.h>

// Sizes (fixed by the reference)
#define N_OBS    20000
#define N_OBS8   2500      // N_OBS/8
#define N_STATES 1024
#define N_ACT    64
#define SDIM     256
#define RFD      2048
#define DECAY    0.9f
#define HALF_O8  1250      // o8 units per half-row (2*1250 = 2500)
#define FLTMAX   3.402823466e+38f

typedef float v4f __attribute__((ext_vector_type(4)));
typedef float v2f __attribute__((ext_vector_type(2)));

__device__ __forceinline__ v4f ntload4(const float* p) {
    return __builtin_nontemporal_load((const v4f*)p);
}

// pack 2 complex (re,im interleaved) into one dword of 4 fp8 e4m3 (OCP on gfx950)
__device__ __forceinline__ unsigned pk4_fp8(float a, float b, float c, float d) {
    unsigned w = __builtin_amdgcn_cvt_pk_fp8_f32(a, b, 0u, false);   // bytes 0,1
    w = __builtin_amdgcn_cvt_pk_fp8_f32(c, d, w, true);              // bytes 2,3
    return w;
}

// ---------------- workspace layout (floats) ----------------
// zeroed region @0 (zeroed by k_fused's spare blocks): score[1024],
// obs_acc[20000], dot0, barrier cnt/gen, pmax[512], psum[512]
#define OFF_SCORE  0
#define OFF_OBSACC 1024
#define OFF_DOT0   21024
#define OFF_CNT    21025
#define OFF_GEN    21026
#define OFF_PMAX   21028                          // [512]
#define OFF_PSUM   (OFF_PMAX + 512)               // [512]
#define ZERO_CNT   (OFF_PSUM + 512)               // 22052 = 5513 float4s
#define OFF_P0RE   22052                          // [2][2048] state0 partials
#define OFF_P0IM   (OFF_P0RE + 2*RFD)
#define OFF_S2RE   (OFF_P0IM + 2*RFD)
#define OFF_S2IM   (OFF_S2RE + RFD)
#define OFF_VWS    (OFF_S2IM + RFD)               // [256]
#define OFF_COSQ   (OFF_VWS + SDIM)               // 34596, %4==0 -> 16B aligned
#define OFF_SINQ   (OFF_COSQ + RFD*N_STATES)
#define OFF_MH8    (OFF_SINQ + RFD*N_STATES)      // fp8 interleaved M copy
#define MH8_FLOATS (RFD * N_OBS8 * 4)             // uint4 per o8 unit -> 82 MB
#define WS_FLOATS  (OFF_MH8 + MH8_FLOATS)         // ~99 MB

// k_fused block map: [0,512) = W@Q GEMM tiles (cos/sin) FIRST,
// 512 = v=V@action, [513,535) = zero accumulators/barrier state,
// [535, 535+4096) = state0 (d,half) streaming blocks (nt read M, fp8 copy).
#define NB_GEMM   512
#define NB_Z      22
#define NB_P1     (RFD * 2)
#define NB_FUSED  (NB_GEMM + 1 + NB_Z + NB_P1)

__global__ __launch_bounds__(256) void k_fused(
    const float* __restrict__ Mre, const float* __restrict__ Mim,
    const float* __restrict__ obs,
    const float* __restrict__ W, const float* __restrict__ Q,
    const float* __restrict__ V, const float* __restrict__ action,
    float* __restrict__ cosQ, float* __restrict__ sinQ,
    float* __restrict__ p0re, float* __restrict__ p0im,
    float* __restrict__ vout, uint4* __restrict__ Mh8,
    float* __restrict__ zbase)
{
    const int b = blockIdx.x;
    const int tid = threadIdx.x;

    if (b < NB_GEMM) {
        // ---- W@Q GEMM tile: theta -> cos/sin ----
        __shared__ float As[16][65];   // [k][m], +1 pad
        __shared__ float Bs[16][64];   // [k][n]
        const int tx = tid & 15;       // n-group (4 cols each)
        const int ty = tid >> 4;       // m-group (4 rows each)
        const int m0 = (b >> 4) * 64;  // 32 m-tiles
        const int n0 = (b & 15) * 64;  // 16 n-tiles
        float c[4][4] = {};
        for (int k0 = 0; k0 < SDIM; k0 += 16) {
            {   // load A: W[m0+m][k0+k]
                int k = tid & 15, mb = tid >> 4;
                #pragma unroll
                for (int j = 0; j < 4; j++)
                    As[k][mb + 16*j] = W[(size_t)(m0 + mb + 16*j) * SDIM + k0 + k];
            }
            {   // load B: Q[k0+k][n0+n]
                int n = tid & 63, kb = tid >> 6;
                #pragma unroll
                for (int j = 0; j < 4; j++)
                    Bs[kb + 4*j][n] = Q[(size_t)(k0 + kb + 4*j) * N_STATES + n0 + n];
            }
            __syncthreads();
            #pragma unroll
            for (int kk = 0; kk < 16; kk++) {
                float a[4], bb[4];
                #pragma unroll
                for (int i = 0; i < 4; i++) a[i] = As[kk][ty*4 + i];
                #pragma unroll
                for (int j = 0; j < 4; j++) bb[j] = Bs[kk][tx*4 + j];
                #pragma unroll
                for (int i = 0; i < 4; i++)
                    #pragma unroll
                    for (int j = 0; j < 4; j++)
                        c[i][j] += a[i] * bb[j];
            }
            __syncthreads();
        }
        #pragma unroll
        for (int i = 0; i < 4; i++) {
            int d = m0 + ty*4 + i;
            #pragma unroll
            for (int j = 0; j < 4; j++) {
                int s = n0 + tx*4 + j;
                float sn, cs;
                sincosf(c[i][j], &sn, &cs);
                cosQ[(size_t)d * N_STATES + s] = cs;
                sinQ[(size_t)d * N_STATES + s] = sn;
            }
        }
    } else if (b == NB_GEMM) {
        // ---- v = V @ action ----
        float acc = 0.f;
        for (int a = 0; a < N_ACT; a++) acc += V[tid * N_ACT + a] * action[a];
        vout[tid] = acc;
    } else if (b < NB_GEMM + 1 + NB_Z) {
        // ---- zero score/obs_acc/dot0/barrier/pmax/psum ----
        int idx = (b - (NB_GEMM + 1)) * 256 + tid;
        if (idx < ZERO_CNT / 4)
            ((float4*)zbase)[idx] = make_float4(0.f, 0.f, 0.f, 0.f);
    } else {
        // ---- state0 partial for (row d, half h); also emit fp8 copy ----
        const int p = b - (NB_GEMM + 1 + NB_Z);
        const int d = p >> 1;
        const int h = p & 1;
        const float* mr = Mre + (size_t)d * N_OBS;
        const float* mi = Mim + (size_t)d * N_OBS;
        uint4* mh = Mh8 + (size_t)d * N_OBS8;
        const float4* ob = (const float4*)obs;
        const int base = h * HALF_O8, lim = base + HALF_O8;
        float ar0 = 0.f, ar1 = 0.f, ai0 = 0.f, ai1 = 0.f;
        int i = base + tid;
        #pragma unroll
        for (int it = 0; it < 5; ++it, i += 256) {
            int ic = i < lim ? i : lim - 1;        // clamp: loads unconditional
            float4 oa = ob[2*ic], obv = ob[2*ic + 1];
            v4f ra = ntload4(mr + 8 * (size_t)ic);
            v4f rb = ntload4(mr + 8 * (size_t)ic + 4);
            v4f qa = ntload4(mi + 8 * (size_t)ic);
            v4f qb = ntload4(mi + 8 * (size_t)ic + 4);
            if (i < lim) {
                uint4 u;
                u.x = pk4_fp8(ra.x, qa.x, ra.y, qa.y);
                u.y = pk4_fp8(ra.z, qa.z, ra.w, qa.w);
                u.z = pk4_fp8(rb.x, qb.x, rb.y, qb.y);
                u.w = pk4_fp8(rb.z, qb.z, rb.w, qb.w);
                mh[ic] = u;
                ar0 += ra.x*oa.x + ra.y*oa.y + ra.z*oa.z + ra.w*oa.w;
                ar1 += rb.x*obv.x + rb.y*obv.y + rb.z*obv.z + rb.w*obv.w;
                ai0 += qa.x*oa.x + qa.y*oa.y + qa.z*oa.z + qa.w*oa.w;
                ai1 += qb.x*obv.x + qb.y*obv.y + qb.z*obv.z + qb.w*obv.w;
            }
        }
        float arr = ar0 + ar1;
        float aii = ai0 + ai1;
        #pragma unroll
        for (int off = 32; off > 0; off >>= 1) {
            arr += __shfl_down(arr, off);
            aii += __shfl_down(aii, off);
        }
        __shared__ float pr[4], pi[4];
        const int wave = tid >> 6, lane = tid & 63;
        if (lane == 0) { pr[wave] = arr; pi[wave] = aii; }
        __syncthreads();
        if (tid == 0) {
            p0re[h * RFD + d] = pr[0] + pr[1] + pr[2] + pr[3];
            p0im[h * RFD + d] = pi[0] + pi[1] + pi[2] + pi[3];
        }
    }
}

// --------- persistent tail: one dispatch, manual grid barrier ---------
// 512 blocks x 256 threads, __launch_bounds__(256,4) => <=128 VGPR, ~6 KB LDS
// => >=4 blocks/CU capacity; 256 CUs * 4 = 1024 slots >= 512 blocks: all
// blocks co-resident under ANY placement -> spin barrier cannot deadlock.
#define NB_TAIL 512

__device__ __forceinline__ void gridbar(unsigned* cnt, unsigned* gen) {
    __syncthreads();                 // each wave drains its own vmem first
    if (threadIdx.x == 0) {
        __threadfence();             // release: block's writes -> device scope
        unsigned g = __hip_atomic_load(gen, __ATOMIC_RELAXED,
                                       __HIP_MEMORY_SCOPE_AGENT);
        unsigned a = __hip_atomic_fetch_add(cnt, 1u, __ATOMIC_ACQ_REL,
                                            __HIP_MEMORY_SCOPE_AGENT);
        if (a == NB_TAIL - 1) {
            __hip_atomic_store(cnt, 0u, __ATOMIC_RELAXED,
                               __HIP_MEMORY_SCOPE_AGENT);
            __hip_atomic_fetch_add(gen, 1u, __ATOMIC_RELEASE,
                                   __HIP_MEMORY_SCOPE_AGENT);
        } else {
            while (__hip_atomic_load(gen, __ATOMIC_ACQUIRE,
                                     __HIP_MEMORY_SCOPE_AGENT) == g)
                __builtin_amdgcn_s_sleep(1);
        }
        __threadfence();             // acquire: invalidate stale cache
    }
    __syncthreads();
}

__global__ __launch_bounds__(256, 4) void k_tail(
    const float* __restrict__ cosQ, const float* __restrict__ sinQ,
    const float* __restrict__ W, const float* __restrict__ vws,
    const float* __restrict__ p0re, const float* __restrict__ p0im,
    float* __restrict__ score,
    float* __restrict__ s2re, float* __restrict__ s2im,
    const uint4* __restrict__ Mh8,
    const float* __restrict__ obs,
    float* __restrict__ oacc, float* __restrict__ dot0,
    unsigned* __restrict__ cnt, unsigned* __restrict__ gen,
    float* __restrict__ pmax, float* __restrict__ psum,
    float* __restrict__ out)
{
    __shared__ float wts_s[1024];
    __shared__ float red[256];
    __shared__ float s1r_s[16], s1i_s[16];
    __shared__ float cs_s[64], ss_s[64];
    __shared__ float bd[4];
    const int b = blockIdx.x;
    const int tid = threadIdx.x;
    const float scale = 1.f / (float)RFD;

    // ---------------- P1: score (512 items: 128 d-chunks x 4 s-chunks) -----
    {
        const int d0 = (b >> 2) * 16;
        const int sc = b & 3;
        const int r = tid >> 4, g = tid & 15;   // row r (16), 16-float seg g
        const float4* wv4 = (const float4*)(W + (size_t)(d0 + r) * SDIM + g * 16);
        const float4* vv4 = (const float4*)(vws + g * 16);
        float th = 0.f;
        #pragma unroll
        for (int j = 0; j < 4; j++) {
            float4 wv = wv4[j], vv = vv4[j];
            th += wv.x*vv.x + wv.y*vv.y + wv.z*vv.z + wv.w*vv.w;
        }
        th += __shfl_xor(th, 8);
        th += __shfl_xor(th, 4);
        th += __shfl_xor(th, 2);
        th += __shfl_xor(th, 1);
        if (g == 0) {
            const int d = d0 + r;
            float re = p0re[d] + p0re[RFD + d];
            float im = p0im[d] + p0im[RFD + d];
            float sn, cs;
            sincosf(th, &sn, &cs);
            s1r_s[r] = re * cs - im * sn;
            s1i_s[r] = re * sn + im * cs;
        }
        __syncthreads();
        const int s = sc * 256 + tid;
        float acc = 0.f;
        #pragma unroll 4
        for (int j = 0; j < 16; j++) {
            int d = d0 + j;
            acc += cosQ[(size_t)d * N_STATES + s] * s1r_s[j]
                 + sinQ[(size_t)d * N_STATES + s] * s1i_s[j];
        }
        atomicAdd(&score[s], acc);
    }
    gridbar(cnt, gen);

    // ---------------- P2: softmax_w (redundant) + state2 (4 rows) + dot0 ---
    {
        float4 v = ((const float4*)score)[tid];
        v.x *= scale; v.y *= scale; v.z *= scale; v.w *= scale;
        float mx = fmaxf(fmaxf(v.x, v.y), fmaxf(v.z, v.w));
        red[tid] = mx; __syncthreads();
        for (int s = 128; s > 0; s >>= 1) {
            if (tid < s) red[tid] = fmaxf(red[tid], red[tid+s]);
            __syncthreads();
        }
        mx = red[0]; __syncthreads();
        float4 e;
        e.x = expf(v.x - mx); e.y = expf(v.y - mx);
        e.z = expf(v.z - mx); e.w = expf(v.w - mx);
        red[tid] = e.x + e.y + e.z + e.w; __syncthreads();
        for (int s = 128; s > 0; s >>= 1) {
            if (tid < s) red[tid] += red[tid+s];
            __syncthreads();
        }
        const float inv = 1.f / red[0];
        __syncthreads();
        e.x *= inv; e.y *= inv; e.z *= inv; e.w *= inv;
        ((float4*)wts_s)[tid] = e;
        __syncthreads();
        // wave w handles row d = b*4 + w
        const int w = tid >> 6, l = tid & 63;
        const int d = b * 4 + w;
        float r1 = 0.f, r2 = 0.f;
        const float* cr = cosQ + (size_t)d * N_STATES;
        const float* sr = sinQ + (size_t)d * N_STATES;
        #pragma unroll 4
        for (int k = 0; k < 16; k++) {
            float wt = wts_s[l + 64*k];
            r1 += cr[l + 64*k] * wt;
            r2 += sr[l + 64*k] * wt;
        }
        #pragma unroll
        for (int off = 32; off > 0; off >>= 1) {
            r1 += __shfl_xor(r1, off);
            r2 += __shfl_xor(r2, off);
        }
        if (l == 0) {
            s2re[d] = r1; s2im[d] = r2;
            float s0r = p0re[d] + p0re[RFD + d];
            float s0i = p0im[d] + p0im[RFD + d];
            bd[w] = s0r * r1 + s0i * r2;
        }
        __syncthreads();
        if (tid == 0)
            atomicAdd(dot0, (bd[0] + bd[1]) + (bd[2] + bd[3]));
    }
    gridbar(cnt, gen);

    // ---------------- P3: obs_acc from fp8 copy (320 items) ----------------
    if (b < 320) {
        const int colgrp = b % 10;             // 10 col-groups of 256 o8 cols
        const int dbase = (b / 10) * 64;       // 32 chunks of 64 rows
        if (tid < 64) { cs_s[tid] = s2re[dbase + tid]; ss_s[tid] = s2im[dbase + tid]; }
        __syncthreads();
        const int idx = colgrp * 256 + tid;    // o8-column index
        if (idx < N_OBS8) {
            const uint4* p = Mh8 + (size_t)dbase * N_OBS8 + idx;
            float a0 = 0.f, a1 = 0.f, a2 = 0.f, a3 = 0.f;
            float a4 = 0.f, a5 = 0.f, a6 = 0.f, a7 = 0.f;
            #pragma unroll 4
            for (int j = 0; j < 64; ++j) {
                uint4 u = p[(size_t)j * N_OBS8];
                float cc = cs_s[j], ss = ss_s[j];
                v2f f0 = __builtin_amdgcn_cvt_pk_f32_fp8(u.x, false);
                v2f f1 = __builtin_amdgcn_cvt_pk_f32_fp8(u.x, true);
                v2f f2 = __builtin_amdgcn_cvt_pk_f32_fp8(u.y, false);
                v2f f3 = __builtin_amdgcn_cvt_pk_f32_fp8(u.y, true);
                v2f f4 = __builtin_amdgcn_cvt_pk_f32_fp8(u.z, false);
                v2f f5 = __builtin_amdgcn_cvt_pk_f32_fp8(u.z, true);
                v2f f6 = __builtin_amdgcn_cvt_pk_f32_fp8(u.w, false);
                v2f f7 = __builtin_amdgcn_cvt_pk_f32_fp8(u.w, true);
                a0 += f0.x*cc + f0.y*ss;
                a1 += f1.x*cc + f1.y*ss;
                a2 += f2.x*cc + f2.y*ss;
                a3 += f3.x*cc + f3.y*ss;
                a4 += f4.x*cc + f4.y*ss;
                a5 += f5.x*cc + f5.y*ss;
                a6 += f6.x*cc + f6.y*ss;
                a7 += f7.x*cc + f7.y*ss;
            }
            float* dst = oacc + idx * 8;
            atomicAdd(dst + 0, a0);
            atomicAdd(dst + 1, a1);
            atomicAdd(dst + 2, a2);
            atomicAdd(dst + 3, a3);
            atomicAdd(dst + 4, a4);
            atomicAdd(dst + 5, a5);
            atomicAdd(dst + 6, a6);
            atomicAdd(dst + 7, a7);
        }
    }
    gridbar(cnt, gen);

    // ---------------- P4a: obs score + per-block max ----------------
    const int o = b * 256 + tid;
    const bool act = o < N_OBS;
    {
        float val = -FLTMAX;
        if (act) {
            val = (DECAY * oacc[o] + obs[o] * dot0[0]) * scale;
            oacc[o] = val;
        }
        red[tid] = val; __syncthreads();
        for (int s = 128; s > 0; s >>= 1) {
            if (tid < s) red[tid] = fmaxf(red[tid], red[tid+s]);
            __syncthreads();
        }
        if (tid == 0) pmax[b] = red[0];
    }
    gridbar(cnt, gen);

    // ---------------- P4b: global max, exp, per-block sum ----------------
    {
        float m = fmaxf(pmax[tid], pmax[tid + 256]);
        red[tid] = m; __syncthreads();
        for (int s = 128; s > 0; s >>= 1) {
            if (tid < s) red[tid] = fmaxf(red[tid], red[tid+s]);
            __syncthreads();
        }
        const float gmax = red[0]; __syncthreads();
        float e = 0.f;
        if (act) {
            e = expf(oacc[o] - gmax);
            oacc[o] = e;
        }
        red[tid] = e; __syncthreads();
        for (int s = 128; s > 0; s >>= 1) {
            if (tid < s) red[tid] += red[tid+s];
            __syncthreads();
        }
        if (tid == 0) psum[b] = red[0];
    }
    gridbar(cnt, gen);

    // ---------------- P4c: global sum, normalize, write ----------------
    {
        red[tid] = psum[tid] + psum[tid + 256]; __syncthreads();
        for (int s = 128; s > 0; s >>= 1) {
            if (tid < s) red[tid] += red[tid+s];
            __syncthreads();
        }
        const float inv = 1.f / red[0];
        if (act) out[o] = oacc[o] * inv;
    }
}

extern "C" void kernel_launch(void* const* d_in, const int* in_sizes, int n_in,
                              void* d_out, int out_size, void* d_ws, size_t ws_size,
                              hipStream_t stream) {
    const float* Q      = (const float*)d_in[0];  // [256,1024]
    const float* V      = (const float*)d_in[1];  // [256,64]
    const float* W      = (const float*)d_in[2];  // [2048,256]
    const float* Mre    = (const float*)d_in[3];  // [2048,20000]
    const float* Mim    = (const float*)d_in[4];  // [2048,20000]
    const float* obs    = (const float*)d_in[5];  // [20000]
    const float* action = (const float*)d_in[6];  // [64]
    float* out = (float*)d_out;                   // [20000]
    float* ws  = (float*)d_ws;

    if (ws_size < (size_t)WS_FLOATS * sizeof(float)) return;

    float*    score = ws + OFF_SCORE;
    float*    oacc  = ws + OFF_OBSACC;
    float*    dot0  = ws + OFF_DOT0;
    unsigned* cnt   = (unsigned*)(ws + OFF_CNT);
    unsigned* gen   = (unsigned*)(ws + OFF_GEN);
    float*    pmax  = ws + OFF_PMAX;
    float*    psum  = ws + OFF_PSUM;
    float*    p0re  = ws + OFF_P0RE;
    float*    p0im  = ws + OFF_P0IM;
    float*    s2re  = ws + OFF_S2RE;
    float*    s2im  = ws + OFF_S2IM;
    float*    vws   = ws + OFF_VWS;
    float*    cosQ  = ws + OFF_COSQ;
    float*    sinQ  = ws + OFF_SINQ;
    uint4*    Mh8   = (uint4*)(ws + OFF_MH8);

    k_fused<<<NB_FUSED, 256, 0, stream>>>(Mre, Mim, obs, W, Q, V, action,
                                          cosQ, sinQ, p0re, p0im, vws, Mh8, ws);
    k_tail<<<NB_TAIL, 256, 0, stream>>>(cosQ, sinQ, W, vws, p0re, p0im, score,
                                        s2re, s2im, Mh8, obs, oacc, dot0,
                                        cnt, gen, pmax, psum, out);
}

// Round 7
// 424.008 us; speedup vs baseline: 1.9074x; 1.9074x over previous
//
#include <hip/hip_runtime.h>
#include <hip/hip_fp16.h>
#include <math.h>

// Sizes (fixed by the reference)
#define N_OBS    20000
#define N_OBS4   5000      // N_OBS/4
#define N_STATES 1024
#define N_ACT    64
#define SDIM     256
#define RFD      2048
#define DECAY    0.9f
#define HALF_O8  1250      // o8 units per half-row (2*1250 = 2500)
#define FLTMAX   3.402823466e+38f

typedef float v4f __attribute__((ext_vector_type(4)));

__device__ __forceinline__ v4f ntload4(const float* p) {
    return __builtin_nontemporal_load((const v4f*)p);
}

// pack (re,im) float4 pair into 8 fp16 (re0,im0,re1,im1,...) = 16 bytes
__device__ __forceinline__ uint4 pack8(v4f re, v4f im) {
    union { __half h[8]; uint4 u; } p;
    p.h[0] = __float2half_rn(re.x); p.h[1] = __float2half_rn(im.x);
    p.h[2] = __float2half_rn(re.y); p.h[3] = __float2half_rn(im.y);
    p.h[4] = __float2half_rn(re.z); p.h[5] = __float2half_rn(im.z);
    p.h[6] = __float2half_rn(re.w); p.h[7] = __float2half_rn(im.w);
    return p.u;
}

// ---------------- workspace layout (floats) ----------------
// zeroed region @0 (zeroed by k_fused's spare blocks): score[1024], obs_acc[20000]
#define OFF_SCORE  0
#define OFF_OBSACC 1024
#define ZERO_CNT   21024                          // 5256 float4s exactly
#define OFF_P0RE   21024                          // [2][2048] state0 half partials
#define OFF_P0IM   (OFF_P0RE + 2*RFD)
#define OFF_S2RE   (OFF_P0IM + 2*RFD)
#define OFF_S2IM   (OFF_S2RE + RFD)
#define OFF_WTS    (OFF_S2IM + RFD)
#define OFF_VWS    (OFF_WTS + N_STATES)
#define OFF_COSQ   (OFF_VWS + SDIM)               // 34592, %4==0 -> 16B aligned
#define OFF_SINQ   (OFF_COSQ + RFD*N_STATES)
#define OFF_MH     (OFF_SINQ + RFD*N_STATES)      // fp16 interleaved M copy
#define MH_FLOATS  (RFD * N_OBS4 * 4)             // uint4 per float4-group, 164 MB
#define WS_FLOATS  (OFF_MH + MH_FLOATS)           // ~181 MB

// k_fused block map: [0,512) = W@Q GEMM tiles (cos/sin) FIRST (long compute
// blocks overlap the HBM streaming below), 512 = v=V@action,
// [513,534) = zero score/obs_acc, [534, 534+4096) = state0 (d,half)
// streaming blocks (nt read M, emit fp16 copy, partial dot).
#define NB_GEMM   512
#define NB_Z      21
#define NB_P1     (RFD * 2)
#define NB_FUSED  (NB_GEMM + 1 + NB_Z + NB_P1)

__global__ __launch_bounds__(256) void k_fused(
    const float* __restrict__ Mre, const float* __restrict__ Mim,
    const float* __restrict__ obs,
    const float* __restrict__ W, const float* __restrict__ Q,
    const float* __restrict__ V, const float* __restrict__ action,
    float* __restrict__ cosQ, float* __restrict__ sinQ,
    float* __restrict__ p0re, float* __restrict__ p0im,
    float* __restrict__ vout, uint4* __restrict__ Mh,
    float* __restrict__ zbase)
{
    const int b = blockIdx.x;
    const int tid = threadIdx.x;

    if (b < NB_GEMM) {
        // ---- W@Q GEMM tile: theta -> cos/sin ----
        __shared__ float As[16][65];   // [k][m], +1 pad
        __shared__ float Bs[16][64];   // [k][n]
        const int tx = tid & 15;       // n-group (4 cols each)
        const int ty = tid >> 4;       // m-group (4 rows each)
        const int m0 = (b >> 4) * 64;  // 32 m-tiles
        const int n0 = (b & 15) * 64;  // 16 n-tiles
        float c[4][4] = {};
        for (int k0 = 0; k0 < SDIM; k0 += 16) {
            {   // load A: W[m0+m][k0+k]
                int k = tid & 15, mb = tid >> 4;
                #pragma unroll
                for (int j = 0; j < 4; j++)
                    As[k][mb + 16*j] = W[(size_t)(m0 + mb + 16*j) * SDIM + k0 + k];
            }
            {   // load B: Q[k0+k][n0+n]
                int n = tid & 63, kb = tid >> 6;
                #pragma unroll
                for (int j = 0; j < 4; j++)
                    Bs[kb + 4*j][n] = Q[(size_t)(k0 + kb + 4*j) * N_STATES + n0 + n];
            }
            __syncthreads();
            #pragma unroll
            for (int kk = 0; kk < 16; kk++) {
                float a[4], bb[4];
                #pragma unroll
                for (int i = 0; i < 4; i++) a[i] = As[kk][ty*4 + i];
                #pragma unroll
                for (int j = 0; j < 4; j++) bb[j] = Bs[kk][tx*4 + j];
                #pragma unroll
                for (int i = 0; i < 4; i++)
                    #pragma unroll
                    for (int j = 0; j < 4; j++)
                        c[i][j] += a[i] * bb[j];
            }
            __syncthreads();
        }
        #pragma unroll
        for (int i = 0; i < 4; i++) {
            int d = m0 + ty*4 + i;
            #pragma unroll
            for (int j = 0; j < 4; j++) {
                int s = n0 + tx*4 + j;
                float sn, cs;
                sincosf(c[i][j], &sn, &cs);
                cosQ[(size_t)d * N_STATES + s] = cs;
                sinQ[(size_t)d * N_STATES + s] = sn;
            }
        }
    } else if (b == NB_GEMM) {
        // ---- v = V @ action ----
        float acc = 0.f;
        for (int a = 0; a < N_ACT; a++) acc += V[tid * N_ACT + a] * action[a];
        vout[tid] = acc;
    } else if (b < NB_GEMM + 1 + NB_Z) {
        // ---- zero the atomic accumulators (score, obs_acc) ----
        int idx = (b - (NB_GEMM + 1)) * 256 + tid;
        if (idx < ZERO_CNT / 4)
            ((float4*)zbase)[idx] = make_float4(0.f, 0.f, 0.f, 0.f);
    } else {
        // ---- state0 partial for (row d, half h); also emit fp16 copy ----
        const int p = b - (NB_GEMM + 1 + NB_Z);
        const int d = p >> 1;
        const int h = p & 1;
        const float* mr = Mre + (size_t)d * N_OBS;
        const float* mi = Mim + (size_t)d * N_OBS;
        uint4* mh = Mh + (size_t)d * N_OBS4;       // uint4 per float4-group
        const float4* ob = (const float4*)obs;
        const int base = h * HALF_O8, lim = base + HALF_O8;  // o8 units
        float ar0 = 0.f, ar1 = 0.f, ai0 = 0.f, ai1 = 0.f;
        int i = base + tid;
        #pragma unroll
        for (int it = 0; it < 5; ++it, i += 256) {
            int ic = i < lim ? i : lim - 1;        // clamp: loads unconditional
            float4 oa = ob[2*ic], obv = ob[2*ic + 1];
            v4f ra = ntload4(mr + 8 * (size_t)ic);
            v4f rb = ntload4(mr + 8 * (size_t)ic + 4);
            v4f qa = ntload4(mi + 8 * (size_t)ic);
            v4f qb = ntload4(mi + 8 * (size_t)ic + 4);
            if (i < lim) {
                mh[2*ic]     = pack8(ra, qa);
                mh[2*ic + 1] = pack8(rb, qb);
                ar0 += ra.x*oa.x + ra.y*oa.y + ra.z*oa.z + ra.w*oa.w;
                ar1 += rb.x*obv.x + rb.y*obv.y + rb.z*obv.z + rb.w*obv.w;
                ai0 += qa.x*oa.x + qa.y*oa.y + qa.z*oa.z + qa.w*oa.w;
                ai1 += qb.x*obv.x + qb.y*obv.y + qb.z*obv.z + qb.w*obv.w;
            }
        }
        float arr = ar0 + ar1;
        float aii = ai0 + ai1;
        #pragma unroll
        for (int off = 32; off > 0; off >>= 1) {
            arr += __shfl_down(arr, off);
            aii += __shfl_down(aii, off);
        }
        __shared__ float pr[4], pi[4];
        const int wave = tid >> 6, lane = tid & 63;
        if (lane == 0) { pr[wave] = arr; pi[wave] = aii; }
        __syncthreads();
        if (tid == 0) {
            p0re[h * RFD + d] = pr[0] + pr[1] + pr[2] + pr[3];
            p0im[h * RFD + d] = pi[0] + pi[1] + pi[2] + pi[3];
        }
    }
}

// K2: fused phase + score. Per block: finalize s0 (2 half partials), rotate
// 32 rows by e^{i W@v} (8 threads/row), then
// score[s] += sum_d cos[d,s]*s1re[d] + sin[d,s]*s1im[d]. grid (4,64).
__global__ __launch_bounds__(256) void k_score(
    const float* __restrict__ cosQ, const float* __restrict__ sinQ,
    const float* __restrict__ W, const float* __restrict__ vws,
    const float* __restrict__ p0re, const float* __restrict__ p0im,
    float* __restrict__ score)
{
    __shared__ float s1r_s[32], s1i_s[32];
    const int tid = threadIdx.x;
    const int d0 = blockIdx.y * 32;
    {
        const int r = tid >> 3, g = tid & 7;   // row r, 32-float segment g
        const float4* wv4 = (const float4*)(W + (size_t)(d0 + r) * SDIM + g * 32);
        const float4* vv4 = (const float4*)(vws + g * 32);
        float th = 0.f;
        #pragma unroll
        for (int j = 0; j < 8; j++) {
            float4 wv = wv4[j], vv = vv4[j];
            th += wv.x*vv.x + wv.y*vv.y + wv.z*vv.z + wv.w*vv.w;
        }
        th += __shfl_xor(th, 4);
        th += __shfl_xor(th, 2);
        th += __shfl_xor(th, 1);
        if (g == 0) {
            const int d = d0 + r;
            float re = p0re[d] + p0re[RFD + d];
            float im = p0im[d] + p0im[RFD + d];
            float sn, cs;
            sincosf(th, &sn, &cs);
            s1r_s[r] = re * cs - im * sn;
            s1i_s[r] = re * sn + im * cs;
        }
    }
    __syncthreads();
    const int s = blockIdx.x * 256 + tid;
    float acc = 0.f;
    #pragma unroll 4
    for (int j = 0; j < 32; j++) {
        int d = d0 + j;
        acc += cosQ[(size_t)d * N_STATES + s] * s1r_s[j]
             + sinQ[(size_t)d * N_STATES + s] * s1i_s[j];
    }
    atomicAdd(&score[s], acc);
}

// K3: weights = softmax(score / 2048), 1024 entries, single block of 256
__global__ __launch_bounds__(256) void k_softmax_w(
    const float* __restrict__ score, float* __restrict__ wts)
{
    __shared__ float red[256];
    const int tid = threadIdx.x;
    const float scale = 1.f / (float)RFD;
    float4 v = ((const float4*)score)[tid];
    v.x *= scale; v.y *= scale; v.z *= scale; v.w *= scale;
    float mx = fmaxf(fmaxf(v.x, v.y), fmaxf(v.z, v.w));
    red[tid] = mx; __syncthreads();
    for (int s = 128; s > 0; s >>= 1) {
        if (tid < s) red[tid] = fmaxf(red[tid], red[tid+s]);
        __syncthreads();
    }
    mx = red[0]; __syncthreads();
    float4 e;
    e.x = expf(v.x - mx); e.y = expf(v.y - mx);
    e.z = expf(v.z - mx); e.w = expf(v.w - mx);
    red[tid] = e.x + e.y + e.z + e.w; __syncthreads();
    for (int s = 128; s > 0; s >>= 1) {
        if (tid < s) red[tid] += red[tid+s];
        __syncthreads();
    }
    const float inv = 1.f / red[0];
    e.x *= inv; e.y *= inv; e.z *= inv; e.w *= inv;
    ((float4*)wts)[tid] = e;
}

// K4: state2 = phi_Q @ weights. Block per row d.
__global__ __launch_bounds__(256) void k_state2(
    const float* __restrict__ cosQ, const float* __restrict__ sinQ,
    const float* __restrict__ wts,
    float* __restrict__ s2re, float* __restrict__ s2im)
{
    __shared__ float r1[256], r2[256];
    const int d = blockIdx.x, tid = threadIdx.x;
    float4 w = ((const float4*)wts)[tid];
    float4 a = ((const float4*)(cosQ + (size_t)d * N_STATES))[tid];
    float4 b = ((const float4*)(sinQ + (size_t)d * N_STATES))[tid];
    r1[tid] = a.x*w.x + a.y*w.y + a.z*w.z + a.w*w.w;
    r2[tid] = b.x*w.x + b.y*w.y + b.z*w.z + b.w*w.w;
    __syncthreads();
    for (int s = 128; s > 0; s >>= 1) {
        if (tid < s) { r1[tid] += r1[tid+s]; r2[tid] += r2[tid+s]; }
        __syncthreads();
    }
    if (tid == 0) { s2re[d] = r1[0]; s2im[d] = r2[0]; }
}

// K5: obs_acc[o] += sum_{d in chunk of 64} re*c + im*s from the interleaved
// fp16 copy. grid (20, 32), 64 rows/block, reverse d order (L3 residency).
__global__ __launch_bounds__(256) void k_obs_acc_h(
    const uint4* __restrict__ Mh,
    const float* __restrict__ s2re, const float* __restrict__ s2im,
    float* __restrict__ obs_acc)
{
    __shared__ float c_s[64], s_s[64];
    const int tid = threadIdx.x;
    const int dbase = (31 - (int)blockIdx.y) * 64;
    if (tid < 64) { c_s[tid] = s2re[dbase + tid]; s_s[tid] = s2im[dbase + tid]; }
    __syncthreads();
    const int idx = blockIdx.x * 256 + tid;   // float4-column group
    if (idx >= N_OBS4) return;
    const uint4* p = Mh + (size_t)dbase * N_OBS4 + idx;
    float4 acc[4];
    #pragma unroll
    for (int u = 0; u < 4; u++) acc[u] = make_float4(0.f, 0.f, 0.f, 0.f);
    #pragma unroll 8
    for (int j = 0; j < 64; ++j) {
        uint4 u = p[(size_t)j * N_OBS4];
        float cc = c_s[j], ss = s_s[j];
        union { unsigned u; __half2 h; } w0, w1, w2, w3;
        w0.u = u.x; w1.u = u.y; w2.u = u.z; w3.u = u.w;
        float2 f0 = __half22float2(w0.h);
        float2 f1 = __half22float2(w1.h);
        float2 f2 = __half22float2(w2.h);
        float2 f3 = __half22float2(w3.h);
        acc[j & 3].x += f0.x*cc + f0.y*ss;
        acc[j & 3].y += f1.x*cc + f1.y*ss;
        acc[j & 3].z += f2.x*cc + f2.y*ss;
        acc[j & 3].w += f3.x*cc + f3.y*ss;
    }
    float4 t;
    t.x = (acc[0].x + acc[1].x) + (acc[2].x + acc[3].x);
    t.y = (acc[0].y + acc[1].y) + (acc[2].y + acc[3].y);
    t.z = (acc[0].z + acc[1].z) + (acc[2].z + acc[3].z);
    t.w = (acc[0].w + acc[1].w) + (acc[2].w + acc[3].w);
    atomicAdd(&obs_acc[idx*4 + 0], t.x);
    atomicAdd(&obs_acc[idx*4 + 1], t.y);
    atomicAdd(&obs_acc[idx*4 + 2], t.z);
    atomicAdd(&obs_acc[idx*4 + 3], t.w);
}

// K6: dot0 = Re(s0 . conj(s2)) from p0 halves;
// out = softmax((0.9*obs_acc + obs*dot0)/2048).
__global__ __launch_bounds__(1024) void k_softmax_obs(
    const float* __restrict__ obs_acc, const float* __restrict__ obs,
    const float* __restrict__ p0re, const float* __restrict__ p0im,
    const float* __restrict__ s2re, const float* __restrict__ s2im,
    float* __restrict__ out)
{
    __shared__ float red[1024];
    const int tid = threadIdx.x;
    float dp = 0.f;
    #pragma unroll
    for (int i = 0; i < 2; i++) {
        int d = tid + i * 1024;
        float re = p0re[d] + p0re[RFD + d];
        float im = p0im[d] + p0im[RFD + d];
        dp += re * s2re[d] + im * s2im[d];
    }
    red[tid] = dp; __syncthreads();
    for (int s = 512; s > 0; s >>= 1) {
        if (tid < s) red[tid] += red[tid+s];
        __syncthreads();
    }
    const float d0 = red[0];
    __syncthreads();
    const float scale = 1.f / (float)RFD;
    float vals[20];
    float mx = -FLTMAX;
    #pragma unroll
    for (int i = 0; i < 20; i++) {
        int idx = tid + i * 1024;
        if (idx < N_OBS) {
            float sc = (DECAY * obs_acc[idx] + obs[idx] * d0) * scale;
            vals[i] = sc;
            mx = fmaxf(mx, sc);
        } else vals[i] = -FLTMAX;
    }
    red[tid] = mx; __syncthreads();
    for (int s = 512; s > 0; s >>= 1) {
        if (tid < s) red[tid] = fmaxf(red[tid], red[tid+s]);
        __syncthreads();
    }
    mx = red[0]; __syncthreads();
    float sum = 0.f;
    #pragma unroll
    for (int i = 0; i < 20; i++) {
        int idx = tid + i * 1024;
        if (idx < N_OBS) {
            vals[i] = expf(vals[i] - mx);
            sum += vals[i];
        }
    }
    red[tid] = sum; __syncthreads();
    for (int s = 512; s > 0; s >>= 1) {
        if (tid < s) red[tid] += red[tid+s];
        __syncthreads();
    }
    const float inv = 1.f / red[0];
    #pragma unroll
    for (int i = 0; i < 20; i++) {
        int idx = tid + i * 1024;
        if (idx < N_OBS) out[idx] = vals[i] * inv;
    }
}

extern "C" void kernel_launch(void* const* d_in, const int* in_sizes, int n_in,
                              void* d_out, int out_size, void* d_ws, size_t ws_size,
                              hipStream_t stream) {
    const float* Q      = (const float*)d_in[0];  // [256,1024]
    const float* V      = (const float*)d_in[1];  // [256,64]
    const float* W      = (const float*)d_in[2];  // [2048,256]
    const float* Mre    = (const float*)d_in[3];  // [2048,20000]
    const float* Mim    = (const float*)d_in[4];  // [2048,20000]
    const float* obs    = (const float*)d_in[5];  // [20000]
    const float* action = (const float*)d_in[6];  // [64]
    float* out = (float*)d_out;                   // [20000]
    float* ws  = (float*)d_ws;

    if (ws_size < (size_t)WS_FLOATS * sizeof(float)) return;

    float* score = ws + OFF_SCORE;
    float* oacc  = ws + OFF_OBSACC;
    float* p0re  = ws + OFF_P0RE;
    float* p0im  = ws + OFF_P0IM;
    float* s2re  = ws + OFF_S2RE;
    float* s2im  = ws + OFF_S2IM;
    float* wts   = ws + OFF_WTS;
    float* vws   = ws + OFF_VWS;
    float* cosQ  = ws + OFF_COSQ;
    float* sinQ  = ws + OFF_SINQ;
    uint4* Mh    = (uint4*)(ws + OFF_MH);

    k_fused<<<NB_FUSED, 256, 0, stream>>>(Mre, Mim, obs, W, Q, V, action,
                                          cosQ, sinQ, p0re, p0im, vws, Mh, ws);
    k_score<<<dim3(4, 64), 256, 0, stream>>>(cosQ, sinQ, W, vws, p0re, p0im, score);
    k_softmax_w<<<1, 256, 0, stream>>>(score, wts);
    k_state2<<<RFD, 256, 0, stream>>>(cosQ, sinQ, wts, s2re, s2im);
    k_obs_acc_h<<<dim3(20, 32), 256, 0, stream>>>(Mh, s2re, s2im, oacc);
    k_softmax_obs<<<1, 1024, 0, stream>>>(oacc, obs, p0re, p0im, s2re, s2im, out);
}